// Round 8
// baseline (124.901 us; speedup 1.0000x reference)
//
#include <hip/hip_runtime.h>

// DAREController route(is_visual=True, training=True)
// B=256 rows, S=32768 tokens. One block per row.
//
// R7 -> R8: attack load-phase memory-level parallelism.
//  - __launch_bounds__(1024, 4): VGPR cap 128 (was 52 -- compiler targeted a
//    useless 2-blocks/CU; grid==#CUs so only 1 block/CU ever resides).
//  - All 16 dwordx4 loads (8 imp + 8 mask) hoisted into register arrays and
//    issued back-to-back before any use: ~16KB/wave in flight vs ~2KB.
//  - Candidate append via wave-ballot aggregation (1 ds_add per wave-group
//    instead of ~600 serialized same-address rtn-atomics per block).
//  Select structure unchanged from R7 (coarse 2048-bin single pass + wave-0
//  ballot finisher) -- R5/R7 proved select cost is not the bottleneck.

#define NB 256
#define NS 32768
#define KAPPA 64
#define NT 1024
#define V4 (NS / NT / 4)      // 8 vec4 per thread
#define NBIN 2048             // top-11-bit buckets
#define NSEG 256              // scan segments (threads)
#define SEGW (NBIN / NSEG)    // 8 bins per scan thread

typedef float f32x4 __attribute__((ext_vector_type(4)));
typedef int   i32x4 __attribute__((ext_vector_type(4)));

__device__ __forceinline__ unsigned int fkey(float f) {
    unsigned int u = __float_as_uint(f);
    return (u & 0x80000000u) ? ~u : (u | 0x80000000u);  // monotone: bigger float -> bigger key
}

__device__ __forceinline__ float unkey(unsigned int k) {
    unsigned int u = (k & 0x80000000u) ? (k ^ 0x80000000u) : ~k;
    return __uint_as_float(u);
}

__global__ __launch_bounds__(NT, 4) void dare_rows(const float* __restrict__ imp,
                                                   const int* __restrict__ mask,
                                                   float* __restrict__ keep,
                                                   float* __restrict__ stats) {
    __shared__ unsigned int hist[NBIN];     // 8 KB
    __shared__ unsigned int cand[NS];       // 128 KB: candidate keys (bucket == b0)
    __shared__ unsigned int wtot[4];
    __shared__ unsigned int sh_mm, sh_eff, sh_cand;
    __shared__ unsigned int sh_b0, sh_rem, sh_thresh;
    __shared__ unsigned int sh_kept, sh_ndrop;
    __shared__ float sh_dsum;

    const int row = blockIdx.x;
    const int tid = threadIdx.x;
    const int lane = tid & 63;
    const f32x4* rimp4  = (const f32x4*)(imp  + (size_t)row * NS);
    const i32x4* rmask4 = (const i32x4*)(mask + (size_t)row * NS);
    f32x4*       rkeep4 = (f32x4*)      (keep + (size_t)row * NS);

    hist[tid] = 0;
    hist[tid + NT] = 0;
    if (tid == 0) {
        sh_mm = 0; sh_eff = 0; sh_cand = 0;
        sh_b0 = 0; sh_rem = 1; sh_thresh = 0;
        sh_kept = 0; sh_ndrop = 0; sh_dsum = 0.0f;
    }
    __syncthreads();   // B1

    // ---- Phase 1: batch-issue ALL loads, then convert (max MLP) ----
    f32x4 vv[V4];
    i32x4 mv[V4];
    #pragma unroll
    for (int i = 0; i < V4; i++) vv[i] = rimp4[tid + i * NT];
    #pragma unroll
    for (int i = 0; i < V4; i++) mv[i] = rmask4[tid + i * NT];

    unsigned int keys[V4 * 4];
    unsigned int effbits = 0, mmbits = 0;
    #pragma unroll
    for (int i = 0; i < V4; i++) {
        const int idx4 = tid + i * NT;
        #pragma unroll
        for (int j = 0; j < 4; j++) {
            const int e = i * 4 + j;
            const int col = idx4 * 4 + j;
            keys[e] = fkey(vv[i][j]);
            const bool mm  = (mv[i][j] != 0);
            const bool eff = mm && (col >= KAPPA);
            mmbits  |= (mm  ? 1u : 0u) << e;
            effbits |= (eff ? 1u : 0u) << e;
        }
    }

    // single histogram pass (top 11 bits)
    #pragma unroll
    for (int e = 0; e < V4 * 4; e++) {
        if ((effbits >> e) & 1u) atomicAdd(&hist[keys[e] >> 21], 1u);
    }

    int mm_local  = __popc(mmbits);
    int eff_local = __popc(effbits);
    #pragma unroll
    for (int off = 32; off; off >>= 1) {
        mm_local  += __shfl_down(mm_local, off);
        eff_local += __shfl_down(eff_local, off);
    }
    if (lane == 0) {
        atomicAdd(&sh_mm,  (unsigned int)mm_local);
        atomicAdd(&sh_eff, (unsigned int)eff_local);
    }
    __syncthreads();   // B2 (hist + counts ready)

    // ---- Phase 2: coarse scan, 256 threads x 8 bins each ----
    unsigned int r[SEGW];
    unsigned int hsum = 0, s = 0;
    if (tid < NSEG) {
        #pragma unroll
        for (int b = 0; b < SEGW; b++) { r[b] = hist[tid * SEGW + b]; hsum += r[b]; }
        s = hsum;
        #pragma unroll
        for (int off = 1; off < 64; off <<= 1) {
            const unsigned int t = __shfl_down(s, off);
            if (lane + off < 64) s += t;
        }
        if (lane == 0) wtot[tid >> 6] = s;
    }
    __syncthreads();   // B3 (wtot ready)
    if (tid < NSEG) {
        unsigned int sfull = s;
        for (int w = (tid >> 6) + 1; w < 4; w++) sfull += wtot[w];
        const float target = fmaxf((float)sh_mm * 0.5f, 1.0f);
        const int k = min((int)target, (int)sh_eff);
        const unsigned int rem = (unsigned int)max(k, 1);
        const unsigned int above = sfull - hsum;   // count in higher segments
        if (sfull >= rem && above < rem) {
            unsigned int cum = above;
            #pragma unroll
            for (int b = SEGW - 1; b >= 0; b--) {
                if (cum + r[b] >= rem) { sh_b0 = tid * SEGW + b; sh_rem = rem - cum; break; }
                cum += r[b];
            }
        }
    }
    __syncthreads();   // B4 (b0, rem ready)

    // ---- Phase 3a: early stores for decided vec4s + candidate append ----
    const unsigned int b0 = sh_b0;
    const bool kpos = (sh_eff > 0);

    int kept_l = 0, ndrop_l = 0;
    float dsum_l = 0.0f;

    // candidate bits
    unsigned int candbits = 0;
    #pragma unroll
    for (int e = 0; e < V4 * 4; e++) {
        const bool is_cand = kpos && ((effbits >> e) & 1u) && ((keys[e] >> 21) == b0);
        candbits |= (is_cand ? 1u : 0u) << e;
    }

    // wave-aggregated append of candidates to LDS
    #pragma unroll
    for (int e = 0; e < V4 * 4; e++) {
        const bool is_cand = (candbits >> e) & 1u;
        const unsigned long long bal = __ballot(is_cand);
        if (bal) {
            const int leader = __ffsll(bal) - 1;
            unsigned int base = 0;
            if (lane == leader) base = atomicAdd(&sh_cand, (unsigned int)__popcll(bal));
            base = __shfl(base, leader);
            if (is_cand) {
                const unsigned int off = (unsigned int)__popcll(bal & ((1ull << lane) - 1ull));
                cand[base + off] = keys[e];
            }
        }
    }

    unsigned int defer = 0;
    #pragma unroll
    for (int i = 0; i < V4; i++) {
        const int idx4 = tid + i * NT;
        const unsigned int nib = (candbits >> (i * 4)) & 0xFu;
        if (nib) {
            defer |= 1u << i;
        } else {
            f32x4 o;
            #pragma unroll
            for (int j = 0; j < 4; j++) {
                const int e = i * 4 + j;
                const int col = idx4 * 4 + j;
                const bool mm  = (mmbits >> e) & 1u;
                const bool eff = (effbits >> e) & 1u;
                const bool hard = kpos && eff && ((keys[e] >> 21) > b0);
                const bool kp = (col < KAPPA) || hard;
                o[j] = kp ? 1.0f : 0.0f;
                kept_l += (kp && mm) ? 1 : 0;
                const bool drop = mm && !kp;
                ndrop_l += drop ? 1 : 0;
                dsum_l += drop ? unkey(keys[e]) : 0.0f;
            }
            rkeep4[idx4] = o;
        }
    }
    __syncthreads();   // B5 (cand array complete)

    // ---- Phase 3b: wave-0 ballot bit-select over candidates ----
    if (tid < 64) {
        const unsigned int cnt = sh_cand;
        if (cnt > 0) {
            unsigned int rem = sh_rem;
            unsigned int pref = 0;
            const int slots = (int)((cnt + 63u) >> 6);
            unsigned int lowreg[16];
            #pragma unroll
            for (int sl = 0; sl < 16; sl++) {
                const unsigned int idx = (unsigned int)lane + ((unsigned int)sl << 6);
                lowreg[sl] = (idx < cnt) ? (cand[idx] & 0x1FFFFFu) : 0xFFFFFFFFu;
            }
            for (int bit = 20; bit >= 0; bit--) {
                const unsigned int hi = pref >> (bit + 1);
                unsigned int cnt1 = 0;
                for (int sl = 0; sl < slots; sl++) {
                    unsigned int lw;
                    if (sl < 16) lw = lowreg[sl];
                    else {
                        const unsigned int idx = (unsigned int)lane + ((unsigned int)sl << 6);
                        lw = (idx < cnt) ? (cand[idx] & 0x1FFFFFu) : 0xFFFFFFFFu;
                    }
                    const bool m = (lw >> (bit + 1)) == hi && ((lw >> bit) & 1u);
                    cnt1 += (unsigned int)__popcll(__ballot(m));
                }
                if (cnt1 >= rem) pref |= 1u << bit; else rem -= cnt1;
            }
            if (lane == 0) sh_thresh = (b0 << 21) | pref;
        }
    }
    __syncthreads();   // B6 (thresh ready)

    // ---- Phase 3c: tail — deferred vec4s with exact threshold ----
    const unsigned int thresh = sh_thresh;
    #pragma unroll
    for (int i = 0; i < V4; i++) {
        if ((defer >> i) & 1u) {
            const int idx4 = tid + i * NT;
            f32x4 o;
            #pragma unroll
            for (int j = 0; j < 4; j++) {
                const int e = i * 4 + j;
                const int col = idx4 * 4 + j;
                const bool mm  = (mmbits >> e) & 1u;
                const bool eff = (effbits >> e) & 1u;
                const bool hard = kpos && eff && (keys[e] >= thresh);
                const bool kp = (col < KAPPA) || hard;
                o[j] = kp ? 1.0f : 0.0f;
                kept_l += (kp && mm) ? 1 : 0;
                const bool drop = mm && !kp;
                ndrop_l += drop ? 1 : 0;
                dsum_l += drop ? unkey(keys[e]) : 0.0f;
            }
            rkeep4[idx4] = o;
        }
    }

    #pragma unroll
    for (int off = 32; off; off >>= 1) {
        kept_l  += __shfl_down(kept_l, off);
        ndrop_l += __shfl_down(ndrop_l, off);
        dsum_l  += __shfl_down(dsum_l, off);
    }
    if (lane == 0) {
        atomicAdd(&sh_kept,  (unsigned int)kept_l);
        atomicAdd(&sh_ndrop, (unsigned int)ndrop_l);
        atomicAdd(&sh_dsum,  dsum_l);
    }
    __syncthreads();   // B7
    if (tid == 0) {
        stats[row * 4 + 0] = (float)sh_kept;
        stats[row * 4 + 1] = (float)sh_mm;
        stats[row * 4 + 2] = (float)sh_ndrop;
        stats[row * 4 + 3] = sh_dsum;
    }
}

__global__ __launch_bounds__(256) void dare_losses(const float* __restrict__ stats,
                                                   float* __restrict__ out) {
    __shared__ float w_a[4], w_h[4], w_n[4], w_d[4];
    const int tid = threadIdx.x;   // one thread per row
    const float kept = stats[tid * 4 + 0];
    const float mmc  = stats[tid * 4 + 1];
    const float nd   = stats[tid * 4 + 2];
    const float ds   = stats[tid * 4 + 3];
    const float ratio = kept / (mmc + 1e-6f);
    float a = fabsf(ratio - 0.5f);          // |ratio - rho|
    float h = fmaxf(0.5f - ratio, 0.0f);    // relu(rho - ratio)
    float n = nd, d = ds;
    #pragma unroll
    for (int off = 32; off; off >>= 1) {
        a += __shfl_down(a, off);
        h += __shfl_down(h, off);
        n += __shfl_down(n, off);
        d += __shfl_down(d, off);
    }
    const int wid = tid >> 6, lane = tid & 63;
    if (lane == 0) { w_a[wid] = a; w_h[wid] = h; w_n[wid] = n; w_d[wid] = d; }
    __syncthreads();
    if (tid == 0) {
        float sa = 0.f, shh = 0.f, sn = 0.f, sd = 0.f;
        for (int w = 0; w < 4; w++) { sa += w_a[w]; shh += w_h[w]; sn += w_n[w]; sd += w_d[w]; }
        out[0] = sa / (float)NB;                                        // 1.0 * loss_ratio
        out[1] = (sn > 0.0f) ? 0.1f * (sd / fmaxf(sn, 1.0f)) : 0.0f;    // 0.1 * loss_soft
        out[2] = shh / (float)NB;                                       // 1.0 * loss_hard
    }
}

extern "C" void kernel_launch(void* const* d_in, const int* in_sizes, int n_in,
                              void* d_out, int out_size, void* d_ws, size_t ws_size,
                              hipStream_t stream) {
    const float* imp  = (const float*)d_in[0];
    const int*   mask = (const int*)d_in[1];
    float* out   = (float*)d_out;
    float* stats = (float*)d_ws;   // 256 rows * 4 floats = 4 KB

    dare_rows<<<NB, NT, 0, stream>>>(imp, mask, out, stats);
    dare_losses<<<1, 256, 0, stream>>>(stats, out + (size_t)NB * NS);
}

// Round 9
// 118.845 us; speedup vs baseline: 1.0510x; 1.0510x over previous
//
#include <hip/hip_runtime.h>

// DAREController route(is_visual=True, training=True)
// B=256 rows, S=32768 tokens. One block per row.
//
// R8 -> R9: async global->LDS staging to fix read-phase MLP.
//  - imp row (128 KB) staged via __builtin_amdgcn_global_load_lds width=16:
//    no result VGPRs -> all 8 per-thread loads in flight at once
//    (~128 KB/CU outstanding vs ~2 KB with the VGPR-bound path).
//  - keys recomputed from LDS each pass (ds_read_b128), freeing 32 VGPRs.
//  - select = R2's proven 4-pass 256-bin radix (R5/R7: select cost ~nil).
//  - contiguous stores (no deferral holes -> WRITE_SIZE back to ~33.5 MB).

#define NB 256
#define NS 32768
#define KAPPA 64
#define NT 1024
#define NW (NT / 64)
#define V4 (NS / NT / 4)   // 8 vec4 per thread

typedef float f32x4 __attribute__((ext_vector_type(4)));
typedef int   i32x4 __attribute__((ext_vector_type(4)));
typedef unsigned int u32;

__device__ __forceinline__ u32 fkey(float f) {
    u32 u = __float_as_uint(f);
    return (u & 0x80000000u) ? ~u : (u | 0x80000000u);  // monotone: bigger float -> bigger key
}

__global__ __launch_bounds__(NT) void dare_rows(const float* __restrict__ imp,
                                                const int* __restrict__ mask,
                                                float* __restrict__ keep,
                                                float* __restrict__ stats) {
    __shared__ float simp[NS];        // 128 KB: staged importance row
    __shared__ u32 hist[256];
    __shared__ u32 wtot[4];
    __shared__ u32 wred_mm[NW], wred_eff[NW];
    __shared__ u32 sh_mm, sh_eff, sh_pref, sh_rem;
    __shared__ u32 sh_kept, sh_ndrop;
    __shared__ float sh_dsum;

    const int row = blockIdx.x;
    const int tid = threadIdx.x;
    const int lane = tid & 63;
    const int wid = tid >> 6;
    const f32x4* rimp4  = (const f32x4*)(imp  + (size_t)row * NS);
    const i32x4* rmask4 = (const i32x4*)(mask + (size_t)row * NS);
    f32x4*       rkeep4 = (f32x4*)      (keep + (size_t)row * NS);

    if (tid < 256) hist[tid] = 0;
    if (tid == 0) { sh_pref = 0; sh_rem = 1; sh_kept = 0; sh_ndrop = 0; sh_dsum = 0.0f; }

    // ---- async stage imp -> LDS (no VGPR results; deep MLP) ----
    #pragma unroll
    for (int i = 0; i < V4; i++) {
        const int idx4 = tid + i * NT;
        __builtin_amdgcn_global_load_lds(
            (const __attribute__((address_space(1))) u32*)(&rimp4[idx4]),
            (__attribute__((address_space(3))) u32*)(&simp[idx4 * 4]),
            16, 0, 0);
    }

    // ---- mask -> regs -> bit masks (overlaps the async staging) ----
    i32x4 mv[V4];
    #pragma unroll
    for (int i = 0; i < V4; i++) mv[i] = rmask4[tid + i * NT];

    u32 mmbits = 0, effbits = 0;
    #pragma unroll
    for (int i = 0; i < V4; i++) {
        const int idx4 = tid + i * NT;
        #pragma unroll
        for (int j = 0; j < 4; j++) {
            const int e = i * 4 + j;
            const int col = idx4 * 4 + j;
            const bool mm  = (mv[i][j] != 0);
            const bool eff = mm && (col >= KAPPA);
            mmbits  |= (mm  ? 1u : 0u) << e;
            effbits |= (eff ? 1u : 0u) << e;
        }
    }
    int mm_local  = __popc(mmbits);
    int eff_local = __popc(effbits);
    #pragma unroll
    for (int off = 32; off; off >>= 1) {
        mm_local  += __shfl_down(mm_local, off);
        eff_local += __shfl_down(eff_local, off);
    }
    if (lane == 0) { wred_mm[wid] = (u32)mm_local; wred_eff[wid] = (u32)eff_local; }

    __syncthreads();   // drains vmcnt: simp staged; hist zeroed; wred ready

    // ---- pass-0 histogram (top byte) from LDS; tid0 folds counts ----
    #pragma unroll
    for (int i = 0; i < V4; i++) {
        const int idx4 = tid + i * NT;
        const f32x4 v = *(const f32x4*)&simp[idx4 * 4];
        #pragma unroll
        for (int j = 0; j < 4; j++) {
            if ((effbits >> (i * 4 + j)) & 1u) atomicAdd(&hist[fkey(v[j]) >> 24], 1u);
        }
    }
    if (tid == 0) {
        u32 sm = 0, se = 0;
        #pragma unroll
        for (int w = 0; w < NW; w++) { sm += wred_mm[w]; se += wred_eff[w]; }
        sh_mm = sm; sh_eff = se;
    }
    __syncthreads();

    // ---- 4 radix passes, parallel suffix-scan bin select ----
    #pragma unroll
    for (int pass = 0; pass < 4; pass++) {
        const int shift = 24 - 8 * pass;

        if (pass > 0) {
            if (tid < 256) hist[tid] = 0;
            __syncthreads();
            const u32 pmask = 0xFFFFFFFFu << (shift + 8);
            const u32 pref = sh_pref;
            #pragma unroll
            for (int i = 0; i < V4; i++) {
                const int idx4 = tid + i * NT;
                const f32x4 v = *(const f32x4*)&simp[idx4 * 4];
                #pragma unroll
                for (int j = 0; j < 4; j++) {
                    const u32 key = fkey(v[j]);
                    const bool match = ((effbits >> (i * 4 + j)) & 1u) && ((key & pmask) == pref);
                    if (match) atomicAdd(&hist[(key >> shift) & 0xFFu], 1u);
                }
            }
            __syncthreads();
        }

        u32 h = 0, s = 0;
        if (tid < 256) {
            h = hist[tid];
            s = h;
            #pragma unroll
            for (int off = 1; off < 64; off <<= 1) {
                const u32 t = __shfl_down(s, off);
                if (lane + off < 64) s += t;
            }
            if (lane == 0) wtot[tid >> 6] = s;
        }
        __syncthreads();
        if (tid < 256) {
            u32 sfull = s;
            for (int w = (tid >> 6) + 1; w < 4; w++) sfull += wtot[w];
            u32 rem;
            if (pass == 0) {
                const float target = fmaxf((float)sh_mm * 0.5f, 1.0f);
                const int k = min((int)target, (int)sh_eff);
                rem = (u32)max(k, 1);
            } else {
                rem = sh_rem;
            }
            if (sfull >= rem && (sfull - h) < rem) {
                sh_pref = (pass == 0) ? ((u32)tid << 24) : (sh_pref | ((u32)tid << shift));
                sh_rem = rem - (sfull - h);
            }
        }
        __syncthreads();
    }

    // ---- write keep mask from LDS + accumulate row stats ----
    const u32 thresh = sh_pref;       // exact key of k-th largest valid value
    const bool kpos = (sh_eff > 0);

    int kept_l = 0, ndrop_l = 0;
    float dsum_l = 0.0f;
    #pragma unroll
    for (int i = 0; i < V4; i++) {
        const int idx4 = tid + i * NT;
        const f32x4 v = *(const f32x4*)&simp[idx4 * 4];
        f32x4 o;
        #pragma unroll
        for (int j = 0; j < 4; j++) {
            const int e = i * 4 + j;
            const int col = idx4 * 4 + j;
            const bool mm  = (mmbits >> e) & 1u;
            const bool eff = (effbits >> e) & 1u;
            const bool hard = kpos && eff && (fkey(v[j]) >= thresh);
            const bool kp = (col < KAPPA) || hard;
            o[j] = kp ? 1.0f : 0.0f;
            kept_l += (kp && mm) ? 1 : 0;
            const bool drop = mm && !kp;
            ndrop_l += drop ? 1 : 0;
            dsum_l += drop ? v[j] : 0.0f;
        }
        rkeep4[idx4] = o;
    }
    #pragma unroll
    for (int off = 32; off; off >>= 1) {
        kept_l  += __shfl_down(kept_l, off);
        ndrop_l += __shfl_down(ndrop_l, off);
        dsum_l  += __shfl_down(dsum_l, off);
    }
    if (lane == 0) {
        atomicAdd(&sh_kept,  (u32)kept_l);
        atomicAdd(&sh_ndrop, (u32)ndrop_l);
        atomicAdd(&sh_dsum,  dsum_l);
    }
    __syncthreads();
    if (tid == 0) {
        stats[row * 4 + 0] = (float)sh_kept;
        stats[row * 4 + 1] = (float)sh_mm;
        stats[row * 4 + 2] = (float)sh_ndrop;
        stats[row * 4 + 3] = sh_dsum;
    }
}

__global__ __launch_bounds__(256) void dare_losses(const float* __restrict__ stats,
                                                   float* __restrict__ out) {
    __shared__ float w_a[4], w_h[4], w_n[4], w_d[4];
    const int tid = threadIdx.x;   // one thread per row
    const float kept = stats[tid * 4 + 0];
    const float mmc  = stats[tid * 4 + 1];
    const float nd   = stats[tid * 4 + 2];
    const float ds   = stats[tid * 4 + 3];
    const float ratio = kept / (mmc + 1e-6f);
    float a = fabsf(ratio - 0.5f);          // |ratio - rho|
    float h = fmaxf(0.5f - ratio, 0.0f);    // relu(rho - ratio)
    float n = nd, d = ds;
    #pragma unroll
    for (int off = 32; off; off >>= 1) {
        a += __shfl_down(a, off);
        h += __shfl_down(h, off);
        n += __shfl_down(n, off);
        d += __shfl_down(d, off);
    }
    const int wid = tid >> 6, lane = tid & 63;
    if (lane == 0) { w_a[wid] = a; w_h[wid] = h; w_n[wid] = n; w_d[wid] = d; }
    __syncthreads();
    if (tid == 0) {
        float sa = 0.f, shh = 0.f, sn = 0.f, sd = 0.f;
        for (int w = 0; w < 4; w++) { sa += w_a[w]; shh += w_h[w]; sn += w_n[w]; sd += w_d[w]; }
        out[0] = sa / (float)NB;                                        // 1.0 * loss_ratio
        out[1] = (sn > 0.0f) ? 0.1f * (sd / fmaxf(sn, 1.0f)) : 0.0f;    // 0.1 * loss_soft
        out[2] = shh / (float)NB;                                       // 1.0 * loss_hard
    }
}

extern "C" void kernel_launch(void* const* d_in, const int* in_sizes, int n_in,
                              void* d_out, int out_size, void* d_ws, size_t ws_size,
                              hipStream_t stream) {
    const float* imp  = (const float*)d_in[0];
    const int*   mask = (const int*)d_in[1];
    float* out   = (float*)d_out;
    float* stats = (float*)d_ws;   // 256 rows * 4 floats = 4 KB

    dare_rows<<<NB, NT, 0, stream>>>(imp, mask, out, stats);
    dare_losses<<<1, 256, 0, stream>>>(stats, out + (size_t)NB * NS);
}

// Round 10
// 113.598 us; speedup vs baseline: 1.0995x; 1.0462x over previous
//
#include <hip/hip_runtime.h>

// DAREController route(is_visual=True, training=True)
// B=256 rows, S=32768 tokens. One block per row.
//
// R9 -> R10: ALL global reads via async global_load_lds (no VGPR landing
// registers anywhere -> deep MLP regardless of register allocator):
//   P1 stage mask -> LDS K (128 KB, async)           [barrier]
//   P2 sweep K: mm/eff bits -> 2 regs/thread; eff-bitmap -> LDS  [barrier]
//   P3 stage imp -> K (reuse region, async)          [barrier]
//   P4 sweep K: fkey + 2048-bin hist (hot bin ~1.3k -> atomic cost ~nil)
//   P5 coarse suffix scan -> bucket b0, rem
//   P6 gather b0-candidates (cap 4096; exact LDS fallback if overflow)
//   P7 wave-0 21-bit ballot select -> exact threshold
//   P8 one contiguous store sweep (no holes -> full-line writes)
// Only 2 fkey sweeps (R9 had 5); no 4-pass radix re-walks.

#define NB 256
#define NS 32768
#define KAPPA 64
#define NT 1024
#define V4 (NS / NT / 4)      // 8 vec4 per thread
#define NBIN 2048             // top-11-bit buckets
#define NSEG 256
#define SEGW (NBIN / NSEG)    // 8 bins per scan thread
#define CAND_CAP 4096

typedef float f32x4 __attribute__((ext_vector_type(4)));
typedef int   i32x4 __attribute__((ext_vector_type(4)));
typedef unsigned int u32;

__device__ __forceinline__ u32 fkey(float f) {
    u32 u = __float_as_uint(f);
    return (u & 0x80000000u) ? ~u : (u | 0x80000000u);  // monotone: bigger float -> bigger key
}

__global__ __launch_bounds__(NT) void dare_rows(const float* __restrict__ imp,
                                                const int* __restrict__ mask,
                                                float* __restrict__ keep,
                                                float* __restrict__ stats) {
    __shared__ float K[NS];           // 128 KB staging (mask first, then imp)
    __shared__ u32 hist[NBIN];        // 8 KB
    __shared__ u32 cand[CAND_CAP];    // 16 KB
    __shared__ u32 bm_eff[NT];        // 4 KB eff-bitmap (fallback + debug)
    __shared__ u32 wtot[4];
    __shared__ u32 sh_mm, sh_eff, sh_cand;
    __shared__ u32 sh_b0, sh_rem, sh_thresh;
    __shared__ u32 sh_kept, sh_ndrop;
    __shared__ float sh_dsum;

    const int row = blockIdx.x;
    const int tid = threadIdx.x;
    const int lane = tid & 63;
    const f32x4* rimp4  = (const f32x4*)(imp  + (size_t)row * NS);
    const i32x4* rmask4 = (const i32x4*)(mask + (size_t)row * NS);
    f32x4*       rkeep4 = (f32x4*)      (keep + (size_t)row * NS);

    // ---- P1: async stage mask -> K; zero hist; init scalars ----
    #pragma unroll
    for (int i = 0; i < V4; i++) {
        const int idx4 = tid + i * NT;
        __builtin_amdgcn_global_load_lds(
            (const __attribute__((address_space(1))) u32*)(&rmask4[idx4]),
            (__attribute__((address_space(3))) u32*)(&K[idx4 * 4]),
            16, 0, 0);
    }
    hist[tid] = 0;
    hist[tid + NT] = 0;
    if (tid == 0) {
        sh_mm = 0; sh_eff = 0; sh_cand = 0;
        sh_b0 = 0; sh_rem = 1; sh_thresh = 0;
        sh_kept = 0; sh_ndrop = 0; sh_dsum = 0.0f;
    }
    __syncthreads();   // mask staged

    // ---- P2: sweep K as ints -> mm/eff bits ----
    const i32x4* Km = (const i32x4*)K;
    u32 mmbits = 0, effbits = 0;
    #pragma unroll
    for (int i = 0; i < V4; i++) {
        const int idx4 = tid + i * NT;
        const i32x4 m = Km[idx4];
        #pragma unroll
        for (int j = 0; j < 4; j++) {
            const int e = i * 4 + j;
            const int col = idx4 * 4 + j;
            const bool mm  = (m[j] != 0);
            const bool eff = mm && (col >= KAPPA);
            mmbits  |= (mm  ? 1u : 0u) << e;
            effbits |= (eff ? 1u : 0u) << e;
        }
    }
    bm_eff[tid] = effbits;
    int mm_local  = __popc(mmbits);
    int eff_local = __popc(effbits);
    #pragma unroll
    for (int off = 32; off; off >>= 1) {
        mm_local  += __shfl_down(mm_local, off);
        eff_local += __shfl_down(eff_local, off);
    }
    if (lane == 0) {
        atomicAdd(&sh_mm,  (u32)mm_local);
        atomicAdd(&sh_eff, (u32)eff_local);
    }
    __syncthreads();   // K reads done; counts ready

    // ---- P3: async stage imp -> K (reuse region) ----
    #pragma unroll
    for (int i = 0; i < V4; i++) {
        const int idx4 = tid + i * NT;
        __builtin_amdgcn_global_load_lds(
            (const __attribute__((address_space(1))) u32*)(&rimp4[idx4]),
            (__attribute__((address_space(3))) u32*)(&K[idx4 * 4]),
            16, 0, 0);
    }
    __syncthreads();   // imp staged

    // ---- P4: hist sweep (2048-bin, top 11 bits) ----
    const f32x4* Kf = (const f32x4*)K;
    #pragma unroll
    for (int i = 0; i < V4; i++) {
        const int idx4 = tid + i * NT;
        const f32x4 v = Kf[idx4];
        #pragma unroll
        for (int j = 0; j < 4; j++) {
            if ((effbits >> (i * 4 + j)) & 1u) atomicAdd(&hist[fkey(v[j]) >> 21], 1u);
        }
    }
    __syncthreads();

    // ---- P5: coarse scan, 256 threads x 8 bins ----
    u32 r[SEGW];
    u32 hsum = 0, s = 0;
    if (tid < NSEG) {
        #pragma unroll
        for (int b = 0; b < SEGW; b++) { r[b] = hist[tid * SEGW + b]; hsum += r[b]; }
        s = hsum;
        #pragma unroll
        for (int off = 1; off < 64; off <<= 1) {
            const u32 t = __shfl_down(s, off);
            if (lane + off < 64) s += t;
        }
        if (lane == 0) wtot[tid >> 6] = s;
    }
    __syncthreads();
    if (tid < NSEG) {
        u32 sfull = s;
        for (int w = (tid >> 6) + 1; w < 4; w++) sfull += wtot[w];
        const float target = fmaxf((float)sh_mm * 0.5f, 1.0f);
        const int k = min((int)target, (int)sh_eff);
        const u32 rem = (u32)max(k, 1);
        const u32 above = sfull - hsum;
        if (sfull >= rem && above < rem) {
            u32 cum = above;
            #pragma unroll
            for (int b = SEGW - 1; b >= 0; b--) {
                if (cum + r[b] >= rem) { sh_b0 = tid * SEGW + b; sh_rem = rem - cum; break; }
                cum += r[b];
            }
        }
    }
    __syncthreads();   // b0, rem ready

    // ---- P6: gather bucket-b0 candidates ----
    const u32 b0 = sh_b0;
    const bool kpos = (sh_eff > 0);
    if (kpos) {
        #pragma unroll
        for (int i = 0; i < V4; i++) {
            const int idx4 = tid + i * NT;
            const f32x4 v = Kf[idx4];
            #pragma unroll
            for (int j = 0; j < 4; j++) {
                if ((effbits >> (i * 4 + j)) & 1u) {
                    const u32 key = fkey(v[j]);
                    if ((key >> 21) == b0) {
                        const u32 pos = atomicAdd(&sh_cand, 1u);
                        if (pos < CAND_CAP) cand[pos] = key;
                    }
                }
            }
        }
    }
    __syncthreads();   // cand complete

    // ---- P7: wave-0 ballot bit-select (low 21 bits) ----
    if (tid < 64 && kpos) {
        const u32 total = sh_cand;
        if (total > 0 && total <= CAND_CAP) {
            u32 rem = sh_rem, pref = 0;
            const int slots = (int)((total + 63u) >> 6);
            for (int bit = 20; bit >= 0; bit--) {
                u32 c1 = 0;
                for (int sl = 0; sl < slots; sl++) {
                    const u32 idx = (u32)lane + ((u32)sl << 6);
                    const u32 lw = (idx < total) ? (cand[idx] & 0x1FFFFFu) : 0xFFFFFFFFu;
                    const bool m = (lw >> (bit + 1)) == (pref >> (bit + 1)) && ((lw >> bit) & 1u);
                    c1 += (u32)__popcll(__ballot(m));
                }
                if (c1 >= rem) pref |= 1u << bit; else rem -= c1;
            }
            if (lane == 0) sh_thresh = (b0 << 21) | pref;
        } else if (total > CAND_CAP) {
            // exact fallback: scan K directly (never taken for N(0,1) data)
            u32 rem = sh_rem, pref = 0;
            for (int bit = 20; bit >= 0; bit--) {
                u32 c1 = 0;
                for (int p = lane; p < NS; p += 64) {
                    const int idx4 = p >> 2;
                    const u32 eb = bm_eff[idx4 & (NT - 1)];
                    const int e = ((idx4 >> 10) << 2) | (p & 3);
                    const u32 key = fkey(K[p]);
                    const bool effb = (eb >> e) & 1u;
                    const bool m = effb && ((key >> 21) == b0) &&
                                   ((key & 0x1FFFFFu) >> (bit + 1)) == (pref >> (bit + 1)) &&
                                   ((key >> bit) & 1u);
                    c1 += (u32)__popcll(__ballot(m));
                }
                if (c1 >= rem) pref |= 1u << bit; else rem -= c1;
            }
            if (lane == 0) sh_thresh = (b0 << 21) | pref;
        }
    }
    __syncthreads();   // thresh ready

    // ---- P8: contiguous store sweep + stats ----
    const u32 thresh = sh_thresh;
    int kept_l = 0, ndrop_l = 0;
    float dsum_l = 0.0f;
    #pragma unroll
    for (int i = 0; i < V4; i++) {
        const int idx4 = tid + i * NT;
        const f32x4 v = Kf[idx4];
        f32x4 o;
        #pragma unroll
        for (int j = 0; j < 4; j++) {
            const int e = i * 4 + j;
            const int col = idx4 * 4 + j;
            const bool mm  = (mmbits >> e) & 1u;
            const bool eff = (effbits >> e) & 1u;
            const bool hard = kpos && eff && (fkey(v[j]) >= thresh);
            const bool kp = (col < KAPPA) || hard;
            o[j] = kp ? 1.0f : 0.0f;
            kept_l += (kp && mm) ? 1 : 0;
            const bool drop = mm && !kp;
            ndrop_l += drop ? 1 : 0;
            dsum_l += drop ? v[j] : 0.0f;
        }
        rkeep4[idx4] = o;
    }
    #pragma unroll
    for (int off = 32; off; off >>= 1) {
        kept_l  += __shfl_down(kept_l, off);
        ndrop_l += __shfl_down(ndrop_l, off);
        dsum_l  += __shfl_down(dsum_l, off);
    }
    if (lane == 0) {
        atomicAdd(&sh_kept,  (u32)kept_l);
        atomicAdd(&sh_ndrop, (u32)ndrop_l);
        atomicAdd(&sh_dsum,  dsum_l);
    }
    __syncthreads();
    if (tid == 0) {
        stats[row * 4 + 0] = (float)sh_kept;
        stats[row * 4 + 1] = (float)sh_mm;
        stats[row * 4 + 2] = (float)sh_ndrop;
        stats[row * 4 + 3] = sh_dsum;
    }
}

__global__ __launch_bounds__(256) void dare_losses(const float* __restrict__ stats,
                                                   float* __restrict__ out) {
    __shared__ float w_a[4], w_h[4], w_n[4], w_d[4];
    const int tid = threadIdx.x;   // one thread per row
    const float kept = stats[tid * 4 + 0];
    const float mmc  = stats[tid * 4 + 1];
    const float nd   = stats[tid * 4 + 2];
    const float ds   = stats[tid * 4 + 3];
    const float ratio = kept / (mmc + 1e-6f);
    float a = fabsf(ratio - 0.5f);          // |ratio - rho|
    float h = fmaxf(0.5f - ratio, 0.0f);    // relu(rho - ratio)
    float n = nd, d = ds;
    #pragma unroll
    for (int off = 32; off; off >>= 1) {
        a += __shfl_down(a, off);
        h += __shfl_down(h, off);
        n += __shfl_down(n, off);
        d += __shfl_down(d, off);
    }
    const int wid = tid >> 6, lane = tid & 63;
    if (lane == 0) { w_a[wid] = a; w_h[wid] = h; w_n[wid] = n; w_d[wid] = d; }
    __syncthreads();
    if (tid == 0) {
        float sa = 0.f, shh = 0.f, sn = 0.f, sd = 0.f;
        for (int w = 0; w < 4; w++) { sa += w_a[w]; shh += w_h[w]; sn += w_n[w]; sd += w_d[w]; }
        out[0] = sa / (float)NB;                                        // 1.0 * loss_ratio
        out[1] = (sn > 0.0f) ? 0.1f * (sd / fmaxf(sn, 1.0f)) : 0.0f;    // 0.1 * loss_soft
        out[2] = shh / (float)NB;                                       // 1.0 * loss_hard
    }
}

extern "C" void kernel_launch(void* const* d_in, const int* in_sizes, int n_in,
                              void* d_out, int out_size, void* d_ws, size_t ws_size,
                              hipStream_t stream) {
    const float* imp  = (const float*)d_in[0];
    const int*   mask = (const int*)d_in[1];
    float* out   = (float*)d_out;
    float* stats = (float*)d_ws;   // 256 rows * 4 floats = 4 KB

    dare_rows<<<NB, NT, 0, stream>>>(imp, mask, out, stats);
    dare_losses<<<1, 256, 0, stream>>>(stats, out + (size_t)NB * NS);
}

// Round 11
// 112.664 us; speedup vs baseline: 1.1086x; 1.0083x over previous
//
#include <hip/hip_runtime.h>

// DAREController route(is_visual=True, training=True)
// B=256 rows, S=32768 tokens. One block per row.
//
// R10 -> R11 (hybrid read path -- the one untried composition):
//  - mask: async global_load_lds -> LDS (zero landing VGPRs, overlaps all of
//    the imp stream); bits extracted in one cheap LDS int-sweep.
//  - imp: VGPR dwordx4 loads, keys computed ONCE and held in registers
//    (R2's proven single-sweep shape) -- with mask loads gone, all 8 imp
//    loads own the landing-register budget and pipeline deeper.
//  - select: R7's coarse 2048-bin hist + wave-0 21-bit ballot finisher
//    (fewest barriers among proven-exact variants).
//  - contiguous vec4 stores (full-line write-combining).

#define NB 256
#define NS 32768
#define KAPPA 64
#define NT 1024
#define V4 (NS / NT / 4)      // 8 vec4 per thread
#define NBIN 2048             // top-11-bit buckets
#define NSEG 256
#define SEGW (NBIN / NSEG)    // 8 bins per scan thread
#define CAND_CAP 4096

typedef float f32x4 __attribute__((ext_vector_type(4)));
typedef int   i32x4 __attribute__((ext_vector_type(4)));
typedef unsigned int u32;

__device__ __forceinline__ u32 fkey(float f) {
    u32 u = __float_as_uint(f);
    return (u & 0x80000000u) ? ~u : (u | 0x80000000u);  // monotone: bigger float -> bigger key
}

__device__ __forceinline__ float unkey(u32 k) {
    u32 u = (k & 0x80000000u) ? (k ^ 0x80000000u) : ~k;
    return __uint_as_float(u);
}

__global__ __launch_bounds__(NT) void dare_rows(const float* __restrict__ imp,
                                                const int* __restrict__ mask,
                                                float* __restrict__ keep,
                                                float* __restrict__ stats) {
    __shared__ int smask[NS];         // 128 KB staged mask (async, no VGPRs)
    __shared__ u32 hist[NBIN];        // 8 KB
    __shared__ u32 cand[CAND_CAP];    // 16 KB
    __shared__ u32 wtot[4];
    __shared__ u32 sh_mm, sh_eff, sh_cand;
    __shared__ u32 sh_b0, sh_rem, sh_thresh;
    __shared__ u32 sh_kept, sh_ndrop;
    __shared__ float sh_dsum;

    const int row = blockIdx.x;
    const int tid = threadIdx.x;
    const int lane = tid & 63;
    const f32x4* rimp4  = (const f32x4*)(imp  + (size_t)row * NS);
    const i32x4* rmask4 = (const i32x4*)(mask + (size_t)row * NS);
    f32x4*       rkeep4 = (f32x4*)      (keep + (size_t)row * NS);

    // ---- P0: fire async mask->LDS stage first (overlaps imp stream) ----
    #pragma unroll
    for (int i = 0; i < V4; i++) {
        const int idx4 = tid + i * NT;
        __builtin_amdgcn_global_load_lds(
            (const __attribute__((address_space(1))) u32*)(&rmask4[idx4]),
            (__attribute__((address_space(3))) u32*)(&smask[idx4 * 4]),
            16, 0, 0);
    }
    hist[tid] = 0;
    hist[tid + NT] = 0;
    if (tid == 0) {
        sh_mm = 0; sh_eff = 0; sh_cand = 0;
        sh_b0 = 0; sh_rem = 1; sh_thresh = 0;
        sh_kept = 0; sh_ndrop = 0; sh_dsum = 0.0f;
    }

    // ---- P1: imp -> VGPR keys (single sweep, keys live in registers) ----
    u32 keys[V4 * 4];
    #pragma unroll
    for (int i = 0; i < V4; i++) {
        const f32x4 v = rimp4[tid + i * NT];
        #pragma unroll
        for (int j = 0; j < 4; j++) keys[i * 4 + j] = fkey(v[j]);
    }
    __syncthreads();   // mask staged (vmcnt drained by barrier), hist zeroed

    // ---- P2: mask bits from LDS + counts + 2048-bin hist ----
    const i32x4* Km = (const i32x4*)smask;
    u32 mmbits = 0, effbits = 0;
    #pragma unroll
    for (int i = 0; i < V4; i++) {
        const int idx4 = tid + i * NT;
        const i32x4 m = Km[idx4];
        #pragma unroll
        for (int j = 0; j < 4; j++) {
            const int e = i * 4 + j;
            const int col = idx4 * 4 + j;
            const bool mm  = (m[j] != 0);
            const bool eff = mm && (col >= KAPPA);
            mmbits  |= (mm  ? 1u : 0u) << e;
            effbits |= (eff ? 1u : 0u) << e;
            if (eff) atomicAdd(&hist[keys[e] >> 21], 1u);
        }
    }
    int mm_local  = __popc(mmbits);
    int eff_local = __popc(effbits);
    #pragma unroll
    for (int off = 32; off; off >>= 1) {
        mm_local  += __shfl_down(mm_local, off);
        eff_local += __shfl_down(eff_local, off);
    }
    if (lane == 0) {
        atomicAdd(&sh_mm,  (u32)mm_local);
        atomicAdd(&sh_eff, (u32)eff_local);
    }
    __syncthreads();   // hist + counts ready

    // ---- P3: coarse scan, 256 threads x 8 bins ----
    u32 r[SEGW];
    u32 hsum = 0, s = 0;
    if (tid < NSEG) {
        #pragma unroll
        for (int b = 0; b < SEGW; b++) { r[b] = hist[tid * SEGW + b]; hsum += r[b]; }
        s = hsum;
        #pragma unroll
        for (int off = 1; off < 64; off <<= 1) {
            const u32 t = __shfl_down(s, off);
            if (lane + off < 64) s += t;
        }
        if (lane == 0) wtot[tid >> 6] = s;
    }
    __syncthreads();
    if (tid < NSEG) {
        u32 sfull = s;
        for (int w = (tid >> 6) + 1; w < 4; w++) sfull += wtot[w];
        const float target = fmaxf((float)sh_mm * 0.5f, 1.0f);
        const int k = min((int)target, (int)sh_eff);
        const u32 rem = (u32)max(k, 1);
        const u32 above = sfull - hsum;
        if (sfull >= rem && above < rem) {
            u32 cum = above;
            #pragma unroll
            for (int b = SEGW - 1; b >= 0; b--) {
                if (cum + r[b] >= rem) { sh_b0 = tid * SEGW + b; sh_rem = rem - cum; break; }
                cum += r[b];
            }
        }
    }
    __syncthreads();   // b0, rem ready

    // ---- P4: gather bucket-b0 candidates (keys already in regs) ----
    const u32 b0 = sh_b0;
    const bool kpos = (sh_eff > 0);
    if (kpos) {
        #pragma unroll
        for (int e = 0; e < V4 * 4; e++) {
            if (((effbits >> e) & 1u) && ((keys[e] >> 21) == b0)) {
                const u32 pos = atomicAdd(&sh_cand, 1u);
                if (pos < CAND_CAP) cand[pos] = keys[e];
            }
        }
    }
    __syncthreads();   // cand complete

    // ---- P5: wave-0 ballot bit-select (low 21 bits) ----
    if (tid < 64 && kpos) {
        const u32 total = sh_cand;
        if (total > 0 && total <= CAND_CAP) {
            u32 rem = sh_rem, pref = 0;
            const int slots = (int)((total + 63u) >> 6);
            for (int bit = 20; bit >= 0; bit--) {
                u32 c1 = 0;
                for (int sl = 0; sl < slots; sl++) {
                    const u32 idx = (u32)lane + ((u32)sl << 6);
                    const u32 lw = (idx < total) ? (cand[idx] & 0x1FFFFFu) : 0xFFFFFFFFu;
                    const bool m = (lw >> (bit + 1)) == (pref >> (bit + 1)) && ((lw >> bit) & 1u);
                    c1 += (u32)__popcll(__ballot(m));
                }
                if (c1 >= rem) pref |= 1u << bit; else rem -= c1;
            }
            if (lane == 0) sh_thresh = (b0 << 21) | pref;
        }
    }
    // overflow fallback (never taken for benchmark data; exact if taken):
    __syncthreads();
    if (kpos && sh_cand > CAND_CAP) {
        // rebuild hist over low bits via 4 extra radix passes in hist[0..255]
        // (uses the R2-proven method, block-wide; rare path)
        u32 pref = b0 << 21, rem = sh_rem;
        for (int shift = 13; shift >= 0; shift -= 8) {   // passes over bits [20:13],[12:5],[4:0 padded]
            const int width = (shift == 13) ? 8 : ((shift == 5) ? 8 : 5);
            const int nb = 1 << width;
            if (tid < 256) hist[tid] = 0;
            __syncthreads();
            const u32 himask = ~((1u << (shift + width)) - 1u);
            #pragma unroll
            for (int e = 0; e < V4 * 4; e++) {
                if (((effbits >> e) & 1u) && ((keys[e] & himask) == (pref & himask)))
                    atomicAdd(&hist[(keys[e] >> shift) & (nb - 1)], 1u);
            }
            __syncthreads();
            if (tid == 0) {
                u32 rr = rem;
                int b = nb - 1;
                for (; b > 0; b--) { const u32 c = hist[b]; if (c >= rr) break; rr -= c; }
                sh_b0 = (u32)b; sh_rem = rr;   // reuse as scratch
            }
            __syncthreads();
            pref |= sh_b0 << shift;
            rem = sh_rem;
            __syncthreads();
        }
        if (tid == 0) sh_thresh = pref;
    }
    __syncthreads();   // thresh ready

    // ---- P6: contiguous store sweep + stats (keys in regs) ----
    const u32 thresh = sh_thresh;
    int kept_l = 0, ndrop_l = 0;
    float dsum_l = 0.0f;
    #pragma unroll
    for (int i = 0; i < V4; i++) {
        const int idx4 = tid + i * NT;
        f32x4 o;
        #pragma unroll
        for (int j = 0; j < 4; j++) {
            const int e = i * 4 + j;
            const int col = idx4 * 4 + j;
            const bool mm  = (mmbits >> e) & 1u;
            const bool eff = (effbits >> e) & 1u;
            const bool hard = kpos && eff && (keys[e] >= thresh);
            const bool kp = (col < KAPPA) || hard;
            o[j] = kp ? 1.0f : 0.0f;
            kept_l += (kp && mm) ? 1 : 0;
            const bool drop = mm && !kp;
            ndrop_l += drop ? 1 : 0;
            dsum_l += drop ? unkey(keys[e]) : 0.0f;
        }
        rkeep4[idx4] = o;
    }
    #pragma unroll
    for (int off = 32; off; off >>= 1) {
        kept_l  += __shfl_down(kept_l, off);
        ndrop_l += __shfl_down(ndrop_l, off);
        dsum_l  += __shfl_down(dsum_l, off);
    }
    if (lane == 0) {
        atomicAdd(&sh_kept,  (u32)kept_l);
        atomicAdd(&sh_ndrop, (u32)ndrop_l);
        atomicAdd(&sh_dsum,  dsum_l);
    }
    __syncthreads();
    if (tid == 0) {
        stats[row * 4 + 0] = (float)sh_kept;
        stats[row * 4 + 1] = (float)sh_mm;
        stats[row * 4 + 2] = (float)sh_ndrop;
        stats[row * 4 + 3] = sh_dsum;
    }
}

__global__ __launch_bounds__(256) void dare_losses(const float* __restrict__ stats,
                                                   float* __restrict__ out) {
    __shared__ float w_a[4], w_h[4], w_n[4], w_d[4];
    const int tid = threadIdx.x;   // one thread per row
    const float kept = stats[tid * 4 + 0];
    const float mmc  = stats[tid * 4 + 1];
    const float nd   = stats[tid * 4 + 2];
    const float ds   = stats[tid * 4 + 3];
    const float ratio = kept / (mmc + 1e-6f);
    float a = fabsf(ratio - 0.5f);          // |ratio - rho|
    float h = fmaxf(0.5f - ratio, 0.0f);    // relu(rho - ratio)
    float n = nd, d = ds;
    #pragma unroll
    for (int off = 32; off; off >>= 1) {
        a += __shfl_down(a, off);
        h += __shfl_down(h, off);
        n += __shfl_down(n, off);
        d += __shfl_down(d, off);
    }
    const int wid = tid >> 6, lane = tid & 63;
    if (lane == 0) { w_a[wid] = a; w_h[wid] = h; w_n[wid] = n; w_d[wid] = d; }
    __syncthreads();
    if (tid == 0) {
        float sa = 0.f, shh = 0.f, sn = 0.f, sd = 0.f;
        for (int w = 0; w < 4; w++) { sa += w_a[w]; shh += w_h[w]; sn += w_n[w]; sd += w_d[w]; }
        out[0] = sa / (float)NB;                                        // 1.0 * loss_ratio
        out[1] = (sn > 0.0f) ? 0.1f * (sd / fmaxf(sn, 1.0f)) : 0.0f;    // 0.1 * loss_soft
        out[2] = shh / (float)NB;                                       // 1.0 * loss_hard
    }
}

extern "C" void kernel_launch(void* const* d_in, const int* in_sizes, int n_in,
                              void* d_out, int out_size, void* d_ws, size_t ws_size,
                              hipStream_t stream) {
    const float* imp  = (const float*)d_in[0];
    const int*   mask = (const int*)d_in[1];
    float* out   = (float*)d_out;
    float* stats = (float*)d_ws;   // 256 rows * 4 floats = 4 KB

    dare_rows<<<NB, NT, 0, stream>>>(imp, mask, out, stats);
    dare_losses<<<1, 256, 0, stream>>>(stats, out + (size_t)NB * NS);
}